// Round 16
// baseline (69.548 us; speedup 1.0000x reference)
//
#include <hip/hip_runtime.h>
#include <hip/hip_bf16.h>
#include <stdint.h>

#define VOCAB 50257
#define HID 512
#define LABELS 64
#define TILEV 32           // vocab cols per block; grid = 1571, KSPLIT=1

typedef __attribute__((ext_vector_type(8))) short bf16x8;
typedef __attribute__((ext_vector_type(4))) float f32x4;

__device__ __forceinline__ ushort f2bf(float x) {
    uint32_t u = __float_as_uint(x);
    return (ushort)((u + 0x7fffu + ((u >> 16) & 1u)) >> 16);   // RNE
}

// ---------------------------------------------------------------------------
// K0: C[l] = b2[l] + sum_h b1[h] * w2[l][h]  (bias kept exactly in fp32)
// ---------------------------------------------------------------------------
__global__ void bias_combine(const float* __restrict__ b1,
                             const float* __restrict__ w2,
                             const float* __restrict__ b2,
                             float* __restrict__ C)
{
    int l = threadIdx.x;   // 64 threads
    float s = b2[l];
    for (int h = 0; h < HID; h += 4) {
        float4 wv = *(const float4*)&w2[l * HID + h];
        float4 bv = *(const float4*)&b1[h];
        s += wv.x * bv.x + wv.y * bv.y + wv.z * bv.z + wv.w * bv.w;
    }
    C[l] = s;
}

// ---------------------------------------------------------------------------
// K1 (fast path): M[v][l] = sum_{h=0..511} w1[h,v]*w2[l,h], bf16 MFMA.
// KSPLIT=1, TILEV=32: grid 1571 (occupancy constraint), w1 read EXACTLY once,
// table write 12.9MB (was 51.5), NO LDS, NO barriers. Per wave: 32v x 16l.
// A-frag: 16 stride-VOCAB scalars (16 lrow-lanes = 64B segment). B-frag: 2
// contiguous float4 from w2 (L2-hot, 128KB). 1-deep named-reg prefetch
// (R10-proven; named sets s0/s1 so the compiler cannot sink the loads).
// C store mapping identical to R13/R14/R15 (thrice hardware-verified).
// ---------------------------------------------------------------------------
#define MFMA_B16(a, b, c) __builtin_amdgcn_mfma_f32_16x16x32_bf16(a, b, c, 0, 0, 0)

#define PACK8(ar, dst)                                                        \
    {                                                                         \
        union { uint32_t u[4]; bf16x8 v; } _x;                                \
        _Pragma("unroll")                                                     \
        for (int j = 0; j < 4; ++j)                                           \
            _x.u[j] = (uint32_t)f2bf(ar[2 * j]) |                             \
                      ((uint32_t)f2bf(ar[2 * j + 1]) << 16);                  \
        dst = _x.v;                                                           \
    }

#define LOADC(ar0, ar1, br, c)                                                \
    {                                                                         \
        const float* gA = &w1[(size_t)((c) * 32 + kg * 8) * VOCAB];           \
        _Pragma("unroll")                                                     \
        for (int j = 0; j < 8; ++j)                                           \
            ar0[j] = ok0 ? gA[(size_t)j * VOCAB + vA0] : 0.f;                 \
        _Pragma("unroll")                                                     \
        for (int j = 0; j < 8; ++j)                                           \
            ar1[j] = ok1 ? gA[(size_t)j * VOCAB + vA1] : 0.f;                 \
        const float* gB = &w2[lB_row * HID + (c) * 32 + kg * 8];              \
        *(float4*)&br[0] = *(const float4*)gB;                                \
        *(float4*)&br[4] = *(const float4*)(gB + 4);                          \
    }

#define COMPC(ar0, ar1, br)                                                   \
    {                                                                         \
        bf16x8 a0, a1, bb;                                                    \
        PACK8(ar0, a0);                                                       \
        PACK8(ar1, a1);                                                       \
        PACK8(br, bb);                                                        \
        acc0 = MFMA_B16(a0, bb, acc0);                                        \
        acc1 = MFMA_B16(a1, bb, acc1);                                        \
    }

__global__ __launch_bounds__(256) void build_mfma(
    const float* __restrict__ w1,   // [HID][VOCAB]
    const float* __restrict__ w2,   // [LABELS][HID]
    float* __restrict__ M)          // [VOCAB][LABELS]
{
    const int t      = threadIdx.x;
    const int lane   = t & 63;
    const int wv     = t >> 6;          // wave 0..3 -> labels wv*16..+15
    const int lrow   = lane & 15;
    const int kg     = lane >> 4;
    const int v0     = blockIdx.x * TILEV;
    const int lbase  = wv * 16;
    const int lB_row = lbase + lrow;    // label this lane supplies for B

    const int vA0 = v0 + lrow;
    const int vA1 = vA0 + 16;
    const bool ok0 = vA0 < VOCAB;
    const bool ok1 = vA1 < VOCAB;

    f32x4 acc0 = {0, 0, 0, 0}, acc1 = {0, 0, 0, 0};

    float s0a[8], s0b[8], s0c[8];   // set 0: A-frag0, A-frag1, B
    float s1a[8], s1b[8], s1c[8];   // set 1

    LOADC(s0a, s0b, s0c, 0);
    LOADC(s1a, s1b, s1c, 1);  COMPC(s0a, s0b, s0c);
    LOADC(s0a, s0b, s0c, 2);  COMPC(s1a, s1b, s1c);
    LOADC(s1a, s1b, s1c, 3);  COMPC(s0a, s0b, s0c);
    LOADC(s0a, s0b, s0c, 4);  COMPC(s1a, s1b, s1c);
    LOADC(s1a, s1b, s1c, 5);  COMPC(s0a, s0b, s0c);
    LOADC(s0a, s0b, s0c, 6);  COMPC(s1a, s1b, s1c);
    LOADC(s1a, s1b, s1c, 7);  COMPC(s0a, s0b, s0c);
    LOADC(s0a, s0b, s0c, 8);  COMPC(s1a, s1b, s1c);
    LOADC(s1a, s1b, s1c, 9);  COMPC(s0a, s0b, s0c);
    LOADC(s0a, s0b, s0c, 10); COMPC(s1a, s1b, s1c);
    LOADC(s1a, s1b, s1c, 11); COMPC(s0a, s0b, s0c);
    LOADC(s0a, s0b, s0c, 12); COMPC(s1a, s1b, s1c);
    LOADC(s1a, s1b, s1c, 13); COMPC(s0a, s0b, s0c);
    LOADC(s0a, s0b, s0c, 14); COMPC(s1a, s1b, s1c);
    LOADC(s1a, s1b, s1c, 15); COMPC(s0a, s0b, s0c);
    COMPC(s1a, s1b, s1c);

    // store: C[row=(kg*4+rr) within 16-frag][col=lrow] ; A-frag m -> v block
#pragma unroll
    for (int rr = 0; rr < 4; ++rr) {
        int vb = v0 + kg * 4 + rr;
        if (vb < VOCAB) M[(size_t)vb * LABELS + lbase + lrow] = acc0[rr];
    }
#pragma unroll
    for (int rr = 0; rr < 4; ++rr) {
        int vb = v0 + 16 + kg * 4 + rr;
        if (vb < VOCAB) M[(size_t)vb * LABELS + lbase + lrow] = acc1[rr];
    }
}

// ---------------------------------------------------------------------------
// K1 fallback (small ws): folded-b1 fp32 single-buffer version (R7, proven).
// ---------------------------------------------------------------------------
__global__ __launch_bounds__(256) void build_partial_folded(
    const float* __restrict__ w1,
    const float* __restrict__ b1,
    const float* __restrict__ w2,
    float* __restrict__ P,
    int klen)
{
    __shared__ float lds_a[32 * 68];
    __shared__ float lds_b[32 * 68];

    const int t     = threadIdx.x;
    const int v0    = blockIdx.x * 64;
    const int hbase = blockIdx.y * klen;
    float* Pout = P + (size_t)blockIdx.y * VOCAB * LABELS;
    const int tx = t & 15;
    const int ty = t >> 4;
    const bool full = (v0 + 64 <= VOCAB);

    float acc[4][4] = {};

    for (int h0 = hbase; h0 < hbase + klen; h0 += 32) {
#pragma unroll
        for (int i = 0; i < 8; ++i) {
            int e   = t + 256 * i;
            int row = e >> 6;
            int col = e & 63;
            int v   = v0 + col;
            float a = (full || v < VOCAB) ? w1[(size_t)(h0 + row) * VOCAB + v] : 0.f;
            lds_a[row * 68 + col] = a + b1[h0 + row];
        }
#pragma unroll
        for (int i = 0; i < 2; ++i) {
            int e   = t + 256 * i;
            int hh4 = e >> 6;
            int l   = e & 63;
            float4 bv = *(const float4*)&w2[l * HID + h0 + hh4 * 4];
            lds_b[(hh4 * 4 + 0) * 68 + l] = bv.x;
            lds_b[(hh4 * 4 + 1) * 68 + l] = bv.y;
            lds_b[(hh4 * 4 + 2) * 68 + l] = bv.z;
            lds_b[(hh4 * 4 + 3) * 68 + l] = bv.w;
        }
        __syncthreads();
#pragma unroll
        for (int hh2 = 0; hh2 < 32; ++hh2) {
            float4 a = *(const float4*)&lds_a[hh2 * 68 + tx * 4];
            float4 b = *(const float4*)&lds_b[hh2 * 68 + ty * 4];
            acc[0][0] += a.x * b.x; acc[0][1] += a.x * b.y; acc[0][2] += a.x * b.z; acc[0][3] += a.x * b.w;
            acc[1][0] += a.y * b.x; acc[1][1] += a.y * b.y; acc[1][2] += a.y * b.z; acc[1][3] += a.y * b.w;
            acc[2][0] += a.z * b.x; acc[2][1] += a.z * b.y; acc[2][2] += a.z * b.z; acc[2][3] += a.z * b.w;
            acc[3][0] += a.w * b.x; acc[3][1] += a.w * b.y; acc[3][2] += a.w * b.z; acc[3][3] += a.w * b.w;
        }
        __syncthreads();
    }

#pragma unroll
    for (int i = 0; i < 4; ++i) {
        int v = v0 + tx * 4 + i;
        if (v < VOCAB) {
            *(float4*)&Pout[(size_t)v * LABELS + ty * 4] =
                make_float4(acc[i][0], acc[i][1], acc[i][2], acc[i][3]);
        }
    }
}

// ---------------------------------------------------------------------------
// K2: out[tok][l] = sum_s P[s][idx[tok]][l] + bias[l]
// ---------------------------------------------------------------------------
__global__ __launch_bounds__(256) void gather_out(
    const int* __restrict__ idx,
    const float* __restrict__ P,
    const float* __restrict__ bias,
    float* __restrict__ out,
    int ntok, int ksplit)
{
    int g   = blockIdx.x * 256 + threadIdx.x;
    int tok = g >> 4;
    int j   = g & 15;
    if (tok >= ntok) return;
    int v = idx[tok];
    float4 s = ((const float4*)bias)[j];
    const float4* p = (const float4*)P + (size_t)v * 16 + j;
    for (int k = 0; k < ksplit; ++k) {
        float4 m = p[(size_t)k * VOCAB * 16];
        s.x += m.x; s.y += m.y; s.z += m.z; s.w += m.w;
    }
    ((float4*)out)[(size_t)tok * 16 + j] = s;
}

// ---------------------------------------------------------------------------
// Fallback (ws too small for any table): direct per-token dot.
// ---------------------------------------------------------------------------
__global__ __launch_bounds__(256) void direct_kernel(
    const int* __restrict__ idx,
    const float* __restrict__ w1,
    const float* __restrict__ b1,
    const float* __restrict__ w2,
    const float* __restrict__ b2,
    float* __restrict__ out,
    int ntok)
{
    int g   = blockIdx.x * 256 + threadIdx.x;
    int tok = g >> 6;
    int l   = g & 63;
    if (tok >= ntok) return;
    int v = idx[tok];
    float acc = b2[l];
    for (int h = 0; h < HID; ++h)
        acc += (w1[(size_t)h * VOCAB + v] + b1[h]) * w2[l * HID + h];
    out[(size_t)tok * 64 + l] = acc;
}

extern "C" void kernel_launch(void* const* d_in, const int* in_sizes, int n_in,
                              void* d_out, int out_size, void* d_ws, size_t ws_size,
                              hipStream_t stream) {
    const int*   idx = (const int*)d_in[0];
    const float* w1  = (const float*)d_in[1];
    const float* b1  = (const float*)d_in[2];
    const float* w2  = (const float*)d_in[3];
    const float* b2  = (const float*)d_in[4];
    float* out = (float*)d_out;
    const int ntok = in_sizes[0];   // 8*4096 = 32768

    const size_t table_bytes = (size_t)VOCAB * LABELS * sizeof(float);  // ~12.9 MB
    const int nblk2 = (ntok * 16 + 255) / 256;                          // 2048

    if (ws_size >= table_bytes + 1024) {
        // fast path: KSPLIT=1 barrier-free MFMA build + exact fp32 bias
        float* M = (float*)d_ws;
        float* C = (float*)((char*)d_ws + table_bytes);
        bias_combine<<<1, 64, 0, stream>>>(b1, w2, b2, C);
        int nblk1 = (VOCAB + TILEV - 1) / TILEV;          // 1571
        build_mfma<<<nblk1, 256, 0, stream>>>(w1, w2, M);
        gather_out<<<nblk2, 256, 0, stream>>>(idx, M, C, out, ntok, 1);
    } else {
        int nblk = (ntok * 64 + 255) / 256;
        direct_kernel<<<nblk, 256, 0, stream>>>(idx, w1, b1, w2, b2, out, ntok);
    }
}

// Round 19
// 51.571 us; speedup vs baseline: 1.3486x; 1.3486x over previous
//
#include <hip/hip_runtime.h>
#include <hip/hip_bf16.h>
#include <stdint.h>

#define VOCAB 50257
#define HID 512
#define LABELS 64
#define KSPLIT 4
#define KLEN 128           // HID / KSPLIT
#define TILEV 128
#define BP 136             // B row pitch in ushorts (128 h + 8 pad) = 272 B

typedef __attribute__((ext_vector_type(8))) short bf16x8;
typedef __attribute__((ext_vector_type(4))) float f32x4;
typedef __attribute__((address_space(1))) const void global_cvoid;
typedef __attribute__((address_space(3))) void lds_void;

__device__ __forceinline__ ushort f2bf(float x) {
    uint32_t u = __float_as_uint(x);
    return (ushort)((u + 0x7fffu + ((u >> 16) & 1u)) >> 16);   // RNE
}

__device__ __forceinline__ bf16x8 ld_frag(const ushort* p) {  // p 8B-aligned
    union { uint2 u[2]; bf16x8 v; } x;
    x.u[0] = *(const uint2*)(p);
    x.u[1] = *(const uint2*)(p + 4);
    return x.v;
}

// ---------------------------------------------------------------------------
// K0: C[l] = b2[l] + sum_h b1[h] * w2[l][h]  (bias kept exactly in fp32)
// ---------------------------------------------------------------------------
__global__ void bias_combine(const float* __restrict__ b1,
                             const float* __restrict__ w2,
                             const float* __restrict__ b2,
                             float* __restrict__ C)
{
    int l = threadIdx.x;   // 64 threads
    float s = b2[l];
    for (int h = 0; h < HID; h += 4) {
        float4 wv = *(const float4*)&w2[l * HID + h];
        float4 bv = *(const float4*)&b1[h];
        s += wv.x * bv.x + wv.y * bv.y + wv.z * bv.z + wv.w * bv.w;
    }
    C[l] = s;
}

// ---------------------------------------------------------------------------
// K1 (fast path): P[s][v][l] = sum_h w1[h,v]*w2[l,h] via bf16 MFMA 16x16x32.
// T3/T4 pipeline: A staged [h][v] fp32 into LDS dbuf via global_load_lds
// (width 4: w1 rows only 4B-aligned). Counted vmcnt(16) + RAW s_barrier per
// chunk -> next chunk's 16 loads stay in flight across barriers (never
// vmcnt(0) in loop). Zero VGPR cost for in-flight data => compiler cannot
// sink the prefetch (R15/R16 failure mode). B staged once bf16 (R14 code).
// A-frags: 8x ds_read_b32 from [h][v] (4-way banks, 1.58x = acceptable),
// packed to bf16. MFMA mapping + stores byte-identical to R13/R14/R15.
// ---------------------------------------------------------------------------
#define MFMA_B16(a, b, c) __builtin_amdgcn_mfma_f32_16x16x32_bf16(a, b, c, 0, 0, 0)

#define PACK8(ar, dst)                                                        \
    {                                                                         \
        union { uint32_t u[4]; bf16x8 v; } _x;                                \
        _Pragma("unroll")                                                     \
        for (int j = 0; j < 4; ++j)                                           \
            _x.u[j] = (uint32_t)f2bf(ar[2 * j]) |                             \
                      ((uint32_t)f2bf(ar[2 * j + 1]) << 16);                  \
        dst = _x.v;                                                           \
    }

// Stage A chunk c into lA[buf]: 32 rows x 128 cols fp32, linear [h][v].
// Wave wv covers rows {4i+wv}, two 64-lane halves per row. Dest is
// wave-uniform base + lane*4 (HW rule); src is per-lane (clamped at edge).
#define STAGE(c, buf)                                                         \
    {                                                                         \
        _Pragma("unroll")                                                     \
        for (int i = 0; i < 8; ++i) {                                         \
            int row = 4 * i + wv;                                             \
            _Pragma("unroll")                                                 \
            for (int half = 0; half < 2; ++half) {                            \
                int vcol = v0 + half * 64 + lane;                             \
                const float* src = w1                                         \
                    + (size_t)(hbase + (c) * 32 + row) * VOCAB                \
                    + (fullA ? vcol : (vcol < VOCAB ? vcol : VOCAB - 1));     \
                __builtin_amdgcn_global_load_lds(                             \
                    (global_cvoid*)src,                                       \
                    (lds_void*)&lA[buf][row * 128 + half * 64],               \
                    4, 0, 0);                                                 \
            }                                                                 \
        }                                                                     \
    }

#define COMPUTE(c, buf)                                                       \
    {                                                                         \
        float a0f[8], a1f[8];                                                 \
        _Pragma("unroll")                                                     \
        for (int j = 0; j < 8; ++j)                                           \
            a0f[j] = lA[buf][(kg * 8 + j) * 128 + wv * 32 + lrow];            \
        _Pragma("unroll")                                                     \
        for (int j = 0; j < 8; ++j)                                           \
            a1f[j] = lA[buf][(kg * 8 + j) * 128 + wv * 32 + 16 + lrow];       \
        bf16x8 a0, a1;                                                        \
        PACK8(a0f, a0);                                                       \
        PACK8(a1f, a1);                                                       \
        const ushort* bb = &lB[lrow * BP + (c) * 32 + kg * 8];                \
        bf16x8 b0  = ld_frag(bb);                                             \
        bf16x8 b1f = ld_frag(bb + 16 * BP);                                   \
        bf16x8 b2f = ld_frag(bb + 32 * BP);                                   \
        bf16x8 b3f = ld_frag(bb + 48 * BP);                                   \
        acc00 = MFMA_B16(a0, b0, acc00);  acc01 = MFMA_B16(a0, b1f, acc01);   \
        acc02 = MFMA_B16(a0, b2f, acc02); acc03 = MFMA_B16(a0, b3f, acc03);   \
        acc10 = MFMA_B16(a1, b0, acc10);  acc11 = MFMA_B16(a1, b1f, acc11);   \
        acc12 = MFMA_B16(a1, b2f, acc12); acc13 = MFMA_B16(a1, b3f, acc13);   \
    }

#define STORE_ONE(accv, m, n)                                                 \
    {                                                                         \
        int vb = v0 + wv * 32 + (m) * 16 + kg * 4;                            \
        int l  = (n) * 16 + lrow;                                             \
        _Pragma("unroll")                                                     \
        for (int rr = 0; rr < 4; ++rr)                                        \
            if (fullA || (vb + rr) < VOCAB)                                   \
                Pout[(size_t)(vb + rr) * LABELS + l] = accv[rr];              \
    }

#define WAITV(n)                                                              \
    asm volatile("s_waitcnt vmcnt(" #n ")" ::: "memory");                     \
    __builtin_amdgcn_s_barrier();                                             \
    __builtin_amdgcn_sched_barrier(0);

#define ENDCOMP                                                               \
    __builtin_amdgcn_sched_barrier(0);                                        \
    __builtin_amdgcn_s_barrier();                                             \
    __builtin_amdgcn_sched_barrier(0);

__global__ __launch_bounds__(256) void build_mfma(
    const float* __restrict__ w1,   // [HID][VOCAB]
    const float* __restrict__ w2,   // [LABELS][HID]
    float* __restrict__ P)          // [KSPLIT][VOCAB][LABELS]
{
    __shared__ float  lA[2][32 * 128];     // [buf][h][v] fp32, 16 KB each
    __shared__ ushort lB[LABELS * BP];     // [l][h] bf16, 17 KB

    const int t     = threadIdx.x;
    const int lane  = t & 63;
    const int wv    = t >> 6;       // wave 0..3 -> v-rows wv*32..+31
    const int lrow  = lane & 15;
    const int kg    = lane >> 4;
    const int v0    = blockIdx.x * TILEV;
    const int hbase = blockIdx.y * KLEN;
    float* Pout = P + (size_t)blockIdx.y * VOCAB * LABELS;
    const bool fullA = (v0 + TILEV <= VOCAB);

    // ---- B stage (R14-proven): 64l x 128h fp32 -> bf16, 8 float4/thread
#pragma unroll
    for (int i = 0; i < 8; ++i) {
        int e  = t + 256 * i;       // 0..2047
        int l  = e >> 5;            // 0..63
        int hq = e & 31;            // float4 index within row
        float4 wv4 = *(const float4*)&w2[l * HID + hbase + hq * 4];
        uint32_t q0 = (uint32_t)f2bf(wv4.x) | ((uint32_t)f2bf(wv4.y) << 16);
        uint32_t q1 = (uint32_t)f2bf(wv4.z) | ((uint32_t)f2bf(wv4.w) << 16);
        *(uint32_t*)&lB[l * BP + hq * 4]     = q0;
        *(uint32_t*)&lB[l * BP + hq * 4 + 2] = q1;
    }
    __builtin_amdgcn_sched_barrier(0);

    // ---- issue A stages for chunks 0,1 (16 loads/wave each; fire-and-forget)
    STAGE(0, 0);
    STAGE(1, 1);
    __builtin_amdgcn_sched_barrier(0);
    asm volatile("s_waitcnt lgkmcnt(0)" ::: "memory");   // B ds_writes done

    f32x4 acc00 = {0,0,0,0}, acc01 = {0,0,0,0}, acc02 = {0,0,0,0}, acc03 = {0,0,0,0};
    f32x4 acc10 = {0,0,0,0}, acc11 = {0,0,0,0}, acc12 = {0,0,0,0}, acc13 = {0,0,0,0};

    // chunk 0: wait stage0 (stage1's 16 stay in flight)
    WAITV(16)
    COMPUTE(0, 0)
    ENDCOMP
    STAGE(2, 0);

    // chunk 1
    WAITV(16)
    COMPUTE(1, 1)
    ENDCOMP
    STAGE(3, 1);

    // chunk 2
    WAITV(16)
    COMPUTE(2, 0)
    ENDCOMP

    // chunk 3: drain
    WAITV(0)
    COMPUTE(3, 1)

    STORE_ONE(acc00, 0, 0); STORE_ONE(acc01, 0, 1);
    STORE_ONE(acc02, 0, 2); STORE_ONE(acc03, 0, 3);
    STORE_ONE(acc10, 1, 0); STORE_ONE(acc11, 1, 1);
    STORE_ONE(acc12, 1, 2); STORE_ONE(acc13, 1, 3);
}

// ---------------------------------------------------------------------------
// K1 fallback (small ws): folded-b1 fp32 single-buffer version (R7, proven).
// ---------------------------------------------------------------------------
__global__ __launch_bounds__(256) void build_partial_folded(
    const float* __restrict__ w1,
    const float* __restrict__ b1,
    const float* __restrict__ w2,
    float* __restrict__ P,
    int klen)
{
    __shared__ float lds_a[32 * 68];
    __shared__ float lds_b[32 * 68];

    const int t     = threadIdx.x;
    const int v0    = blockIdx.x * 64;
    const int hbase = blockIdx.y * klen;
    float* Pout = P + (size_t)blockIdx.y * VOCAB * LABELS;
    const int tx = t & 15;
    const int ty = t >> 4;
    const bool full = (v0 + 64 <= VOCAB);

    float acc[4][4] = {};

    for (int h0 = hbase; h0 < hbase + klen; h0 += 32) {
#pragma unroll
        for (int i = 0; i < 8; ++i) {
            int e   = t + 256 * i;
            int row = e >> 6;
            int col = e & 63;
            int v   = v0 + col;
            float a = (full || v < VOCAB) ? w1[(size_t)(h0 + row) * VOCAB + v] : 0.f;
            lds_a[row * 68 + col] = a + b1[h0 + row];
        }
#pragma unroll
        for (int i = 0; i < 2; ++i) {
            int e   = t + 256 * i;
            int hh4 = e >> 6;
            int l   = e & 63;
            float4 bv = *(const float4*)&w2[l * HID + h0 + hh4 * 4];
            lds_b[(hh4 * 4 + 0) * 68 + l] = bv.x;
            lds_b[(hh4 * 4 + 1) * 68 + l] = bv.y;
            lds_b[(hh4 * 4 + 2) * 68 + l] = bv.z;
            lds_b[(hh4 * 4 + 3) * 68 + l] = bv.w;
        }
        __syncthreads();
#pragma unroll
        for (int hh2 = 0; hh2 < 32; ++hh2) {
            float4 a = *(const float4*)&lds_a[hh2 * 68 + tx * 4];
            float4 b = *(const float4*)&lds_b[hh2 * 68 + ty * 4];
            acc[0][0] += a.x * b.x; acc[0][1] += a.x * b.y; acc[0][2] += a.x * b.z; acc[0][3] += a.x * b.w;
            acc[1][0] += a.y * b.x; acc[1][1] += a.y * b.y; acc[1][2] += a.y * b.z; acc[1][3] += a.y * b.w;
            acc[2][0] += a.z * b.x; acc[2][1] += a.z * b.y; acc[2][2] += a.z * b.z; acc[2][3] += a.z * b.w;
            acc[3][0] += a.w * b.x; acc[3][1] += a.w * b.y; acc[3][2] += a.w * b.z; acc[3][3] += a.w * b.w;
        }
        __syncthreads();
    }

#pragma unroll
    for (int i = 0; i < 4; ++i) {
        int v = v0 + tx * 4 + i;
        if (v < VOCAB) {
            *(float4*)&Pout[(size_t)v * LABELS + ty * 4] =
                make_float4(acc[i][0], acc[i][1], acc[i][2], acc[i][3]);
        }
    }
}

// ---------------------------------------------------------------------------
// K2: out[tok][l] = sum_s P[s][idx[tok]][l] + bias[l]
// ---------------------------------------------------------------------------
__global__ __launch_bounds__(256) void gather_out(
    const int* __restrict__ idx,
    const float* __restrict__ P,
    const float* __restrict__ bias,
    float* __restrict__ out,
    int ntok, int ksplit)
{
    int g   = blockIdx.x * 256 + threadIdx.x;
    int tok = g >> 4;
    int j   = g & 15;
    if (tok >= ntok) return;
    int v = idx[tok];
    float4 s = ((const float4*)bias)[j];
    const float4* p = (const float4*)P + (size_t)v * 16 + j;
    for (int k = 0; k < ksplit; ++k) {
        float4 m = p[(size_t)k * VOCAB * 16];
        s.x += m.x; s.y += m.y; s.z += m.z; s.w += m.w;
    }
    ((float4*)out)[(size_t)tok * 16 + j] = s;
}

// ---------------------------------------------------------------------------
// Fallback (ws too small for any table): direct per-token dot.
// ---------------------------------------------------------------------------
__global__ __launch_bounds__(256) void direct_kernel(
    const int* __restrict__ idx,
    const float* __restrict__ w1,
    const float* __restrict__ b1,
    const float* __restrict__ w2,
    const float* __restrict__ b2,
    float* __restrict__ out,
    int ntok)
{
    int g   = blockIdx.x * 256 + threadIdx.x;
    int tok = g >> 6;
    int l   = g & 63;
    if (tok >= ntok) return;
    int v = idx[tok];
    float acc = b2[l];
    for (int h = 0; h < HID; ++h)
        acc += (w1[(size_t)h * VOCAB + v] + b1[h]) * w2[l * HID + h];
    out[(size_t)tok * 64 + l] = acc;
}

extern "C" void kernel_launch(void* const* d_in, const int* in_sizes, int n_in,
                              void* d_out, int out_size, void* d_ws, size_t ws_size,
                              hipStream_t stream) {
    const int*   idx = (const int*)d_in[0];
    const float* w1  = (const float*)d_in[1];
    const float* b1  = (const float*)d_in[2];
    const float* w2  = (const float*)d_in[3];
    const float* b2  = (const float*)d_in[4];
    float* out = (float*)d_out;
    const int ntok = in_sizes[0];   // 8*4096 = 32768

    const size_t table_bytes = (size_t)VOCAB * LABELS * sizeof(float);  // ~12.9 MB
    const int nblk2 = (ntok * 16 + 255) / 256;                          // 2048

    if (ws_size >= (size_t)KSPLIT * table_bytes + 1024) {
        // fast path: T3/T4 pipelined MFMA build + exact fp32 bias in ws tail
        float* P = (float*)d_ws;
        float* C = (float*)((char*)d_ws + (size_t)KSPLIT * table_bytes);
        bias_combine<<<1, 64, 0, stream>>>(b1, w2, b2, C);
        dim3 grid1((VOCAB + TILEV - 1) / TILEV, KSPLIT);   // 393 x 4 = 1572
        build_mfma<<<grid1, 256, 0, stream>>>(w1, w2, P);
        gather_out<<<nblk2, 256, 0, stream>>>(idx, P, C, out, ntok, KSPLIT);
    } else {
        int ksplit = 0;
        if      (ws_size >= 4 * table_bytes) ksplit = 4;
        else if (ws_size >= 2 * table_bytes) ksplit = 2;
        else if (ws_size >= 1 * table_bytes) ksplit = 1;
        if (ksplit > 0) {
            float* P = (float*)d_ws;
            dim3 grid1((VOCAB + 63) / 64, ksplit);
            build_partial_folded<<<grid1, 256, 0, stream>>>(w1, b1, w2, P, HID / ksplit);
            gather_out<<<nblk2, 256, 0, stream>>>(idx, P, b2, out, ntok, ksplit);
        } else {
            int nblk = (ntok * 64 + 255) / 256;
            direct_kernel<<<nblk, 256, 0, stream>>>(idx, w1, b1, w2, b2, out, ntok);
        }
    }
}

// Round 23
// 43.778 us; speedup vs baseline: 1.5886x; 1.1780x over previous
//
#include <hip/hip_runtime.h>
#include <hip/hip_bf16.h>
#include <stdint.h>

#define VOCAB 50257
#define HID 512
#define LABELS 64
#define KSPLIT 2
#define KLEN 256           // HID / KSPLIT
#define TILEV 64
#define BP 264             // B row pitch in ushorts (256 h + 8 pad) = 528 B

typedef __attribute__((ext_vector_type(8))) short bf16x8;
typedef __attribute__((ext_vector_type(4))) float f32x4;

__device__ __forceinline__ ushort f2bf(float x) {
    uint32_t u = __float_as_uint(x);
    return (ushort)((u + 0x7fffu + ((u >> 16) & 1u)) >> 16);   // RNE
}

__device__ __forceinline__ bf16x8 ld_frag(const ushort* p) {  // p 8B-aligned
    union { uint2 u[2]; bf16x8 v; } x;
    x.u[0] = *(const uint2*)(p);
    x.u[1] = *(const uint2*)(p + 4);
    return x.v;
}

// ---------------------------------------------------------------------------
// K1 (fast path): P[s][v][l] = sum_{h in split s} w1[h,v]*w2[l,h], bf16 MFMA.
// R14 inner structure unchanged (direct-A global->reg, B-in-LDS bf16, one
// barrier, same MFMA/store mapping — thrice hardware-verified). Deltas:
//  - KSPLIT 4->2 via TILEV=64 / 128-thread blocks: grid (786,2)=1572 keeps
//    the >=1500-block occupancy constraint; table writes 51.5->25.7 MB,
//    gather partial reads 32->16 MB.
//  - bias_combine merged into this grid (block x==786, y==0): one less
//    launch, bias runs concurrently with the build.
// ---------------------------------------------------------------------------
#define MFMA_B16(a, b, c) __builtin_amdgcn_mfma_f32_16x16x32_bf16(a, b, c, 0, 0, 0)

#define PACK8(ar, dst)                                                        \
    {                                                                         \
        union { uint32_t u[4]; bf16x8 v; } _x;                                \
        _Pragma("unroll")                                                     \
        for (int j = 0; j < 4; ++j)                                           \
            _x.u[j] = (uint32_t)f2bf(ar[2 * j]) |                             \
                      ((uint32_t)f2bf(ar[2 * j + 1]) << 16);                  \
        dst = _x.v;                                                           \
    }

#define STORE_ONE(accv, m, n)                                                 \
    {                                                                         \
        int vb = v0 + wv * 32 + (m) * 16 + kg * 4;                            \
        int l  = (n) * 16 + lrow;                                             \
        _Pragma("unroll")                                                     \
        for (int rr = 0; rr < 4; ++rr)                                        \
            if (fullA || (vb + rr) < VOCAB)                                   \
                Pout[(size_t)(vb + rr) * LABELS + l] = accv[rr];              \
    }

__global__ __launch_bounds__(128) void build_mfma(
    const float* __restrict__ w1,   // [HID][VOCAB]
    const float* __restrict__ w2,   // [LABELS][HID]
    const float* __restrict__ b1,   // [HID]
    const float* __restrict__ b2,   // [LABELS]
    float* __restrict__ P,          // [KSPLIT][VOCAB][LABELS]
    float* __restrict__ C)          // [LABELS] combined bias
{
    const int t = threadIdx.x;      // 0..127

    // ---- merged bias block (one per grid; y==0 only) ----
    if (blockIdx.x == (VOCAB + TILEV - 1) / TILEV) {
        if (blockIdx.y == 0 && t < LABELS) {
            float s = b2[t];
            for (int h = 0; h < HID; h += 4) {
                float4 wv4 = *(const float4*)&w2[t * HID + h];
                float4 bv4 = *(const float4*)&b1[h];
                s += wv4.x * bv4.x + wv4.y * bv4.y + wv4.z * bv4.z + wv4.w * bv4.w;
            }
            C[t] = s;
        }
        return;
    }

    __shared__ ushort lB[LABELS * BP];     // [l][h] bf16 w2 K-slice (~33 KB)

    const int lane  = t & 63;
    const int wv    = t >> 6;       // wave 0..1 -> v-rows wv*32..+31
    const int lrow  = lane & 15;
    const int kg    = lane >> 4;
    const int v0    = blockIdx.x * TILEV;
    const int hbase = blockIdx.y * KLEN;
    float* Pout = P + (size_t)blockIdx.y * VOCAB * LABELS;
    const bool fullA = (v0 + TILEV <= VOCAB);

    const int vA0 = v0 + wv * 32 + lrow;
    const int vA1 = vA0 + 16;
    const bool ok0 = fullA || (vA0 < VOCAB);
    const bool ok1 = fullA || (vA1 < VOCAB);

    // ---- stage B once: 64l x 256h fp32 -> bf16. 32 float4 per thread.
#pragma unroll
    for (int i = 0; i < 32; ++i) {
        int e  = t + 128 * i;       // 0..4095
        int l  = e >> 6;            // 0..63
        int hq = e & 63;            // float4 index within row
        float4 wv4 = *(const float4*)&w2[l * HID + hbase + hq * 4];
        uint32_t q0 = (uint32_t)f2bf(wv4.x) | ((uint32_t)f2bf(wv4.y) << 16);
        uint32_t q1 = (uint32_t)f2bf(wv4.z) | ((uint32_t)f2bf(wv4.w) << 16);
        *(uint32_t*)&lB[l * BP + hq * 4]     = q0;
        *(uint32_t*)&lB[l * BP + hq * 4 + 2] = q1;
    }
    __syncthreads();                // the only barrier

    f32x4 acc00 = {0,0,0,0}, acc01 = {0,0,0,0}, acc02 = {0,0,0,0}, acc03 = {0,0,0,0};
    f32x4 acc10 = {0,0,0,0}, acc11 = {0,0,0,0}, acc12 = {0,0,0,0}, acc13 = {0,0,0,0};

#pragma unroll 2
    for (int c = 0; c < KLEN / 32; ++c) {   // 8 chunks
        float ar0[8], ar1[8];
        {
            const float* g = &w1[(size_t)(hbase + c * 32 + kg * 8) * VOCAB];
#pragma unroll
            for (int j = 0; j < 8; ++j)
                ar0[j] = ok0 ? g[(size_t)j * VOCAB + vA0] : 0.f;
#pragma unroll
            for (int j = 0; j < 8; ++j)
                ar1[j] = ok1 ? g[(size_t)j * VOCAB + vA1] : 0.f;
        }
        bf16x8 a0, a1;
        PACK8(ar0, a0);
        PACK8(ar1, a1);
        const ushort* bb = &lB[lrow * BP + c * 32 + kg * 8];
        bf16x8 b0  = ld_frag(bb);
        bf16x8 b1f = ld_frag(bb + 16 * BP);
        bf16x8 b2f = ld_frag(bb + 32 * BP);
        bf16x8 b3f = ld_frag(bb + 48 * BP);
        acc00 = MFMA_B16(a0, b0, acc00);  acc01 = MFMA_B16(a0, b1f, acc01);
        acc02 = MFMA_B16(a0, b2f, acc02); acc03 = MFMA_B16(a0, b3f, acc03);
        acc10 = MFMA_B16(a1, b0, acc10);  acc11 = MFMA_B16(a1, b1f, acc11);
        acc12 = MFMA_B16(a1, b2f, acc12); acc13 = MFMA_B16(a1, b3f, acc13);
    }

    STORE_ONE(acc00, 0, 0); STORE_ONE(acc01, 0, 1);
    STORE_ONE(acc02, 0, 2); STORE_ONE(acc03, 0, 3);
    STORE_ONE(acc10, 1, 0); STORE_ONE(acc11, 1, 1);
    STORE_ONE(acc12, 1, 2); STORE_ONE(acc13, 1, 3);
}

// ---------------------------------------------------------------------------
// K1 fallback (small ws): folded-b1 fp32 single-buffer version (R7, proven).
// ---------------------------------------------------------------------------
__global__ __launch_bounds__(256) void build_partial_folded(
    const float* __restrict__ w1,
    const float* __restrict__ b1,
    const float* __restrict__ w2,
    float* __restrict__ P,
    int klen)
{
    __shared__ float lds_a[32 * 68];
    __shared__ float lds_b[32 * 68];

    const int t     = threadIdx.x;
    const int v0    = blockIdx.x * 64;
    const int hbase = blockIdx.y * klen;
    float* Pout = P + (size_t)blockIdx.y * VOCAB * LABELS;
    const int tx = t & 15;
    const int ty = t >> 4;
    const bool full = (v0 + 64 <= VOCAB);

    float acc[4][4] = {};

    for (int h0 = hbase; h0 < hbase + klen; h0 += 32) {
#pragma unroll
        for (int i = 0; i < 8; ++i) {
            int e   = t + 256 * i;
            int row = e >> 6;
            int col = e & 63;
            int v   = v0 + col;
            float a = (full || v < VOCAB) ? w1[(size_t)(h0 + row) * VOCAB + v] : 0.f;
            lds_a[row * 68 + col] = a + b1[h0 + row];
        }
#pragma unroll
        for (int i = 0; i < 2; ++i) {
            int e   = t + 256 * i;
            int hh4 = e >> 6;
            int l   = e & 63;
            float4 bv = *(const float4*)&w2[l * HID + h0 + hh4 * 4];
            lds_b[(hh4 * 4 + 0) * 68 + l] = bv.x;
            lds_b[(hh4 * 4 + 1) * 68 + l] = bv.y;
            lds_b[(hh4 * 4 + 2) * 68 + l] = bv.z;
            lds_b[(hh4 * 4 + 3) * 68 + l] = bv.w;
        }
        __syncthreads();
#pragma unroll
        for (int hh2 = 0; hh2 < 32; ++hh2) {
            float4 a = *(const float4*)&lds_a[hh2 * 68 + tx * 4];
            float4 b = *(const float4*)&lds_b[hh2 * 68 + ty * 4];
            acc[0][0] += a.x * b.x; acc[0][1] += a.x * b.y; acc[0][2] += a.x * b.z; acc[0][3] += a.x * b.w;
            acc[1][0] += a.y * b.x; acc[1][1] += a.y * b.y; acc[1][2] += a.y * b.z; acc[1][3] += a.y * b.w;
            acc[2][0] += a.z * b.x; acc[2][1] += a.z * b.y; acc[2][2] += a.z * b.z; acc[2][3] += a.z * b.w;
            acc[3][0] += a.w * b.x; acc[3][1] += a.w * b.y; acc[3][2] += a.w * b.z; acc[3][3] += a.w * b.w;
        }
        __syncthreads();
    }

#pragma unroll
    for (int i = 0; i < 4; ++i) {
        int v = v0 + tx * 4 + i;
        if (v < VOCAB) {
            *(float4*)&Pout[(size_t)v * LABELS + ty * 4] =
                make_float4(acc[i][0], acc[i][1], acc[i][2], acc[i][3]);
        }
    }
}

// ---------------------------------------------------------------------------
// K2: out[tok][l] = sum_s P[s][idx[tok]][l] + bias[l]
// ---------------------------------------------------------------------------
__global__ __launch_bounds__(256) void gather_out(
    const int* __restrict__ idx,
    const float* __restrict__ P,
    const float* __restrict__ bias,
    float* __restrict__ out,
    int ntok, int ksplit)
{
    int g   = blockIdx.x * 256 + threadIdx.x;
    int tok = g >> 4;
    int j   = g & 15;
    if (tok >= ntok) return;
    int v = idx[tok];
    float4 s = ((const float4*)bias)[j];
    const float4* p = (const float4*)P + (size_t)v * 16 + j;
    for (int k = 0; k < ksplit; ++k) {
        float4 m = p[(size_t)k * VOCAB * 16];
        s.x += m.x; s.y += m.y; s.z += m.z; s.w += m.w;
    }
    ((float4*)out)[(size_t)tok * 16 + j] = s;
}

// ---------------------------------------------------------------------------
// Fallback (ws too small for any table): direct per-token dot.
// ---------------------------------------------------------------------------
__global__ __launch_bounds__(256) void direct_kernel(
    const int* __restrict__ idx,
    const float* __restrict__ w1,
    const float* __restrict__ b1,
    const float* __restrict__ w2,
    const float* __restrict__ b2,
    float* __restrict__ out,
    int ntok)
{
    int g   = blockIdx.x * 256 + threadIdx.x;
    int tok = g >> 6;
    int l   = g & 63;
    if (tok >= ntok) return;
    int v = idx[tok];
    float acc = b2[l];
    for (int h = 0; h < HID; ++h)
        acc += (w1[(size_t)h * VOCAB + v] + b1[h]) * w2[l * HID + h];
    out[(size_t)tok * 64 + l] = acc;
}

extern "C" void kernel_launch(void* const* d_in, const int* in_sizes, int n_in,
                              void* d_out, int out_size, void* d_ws, size_t ws_size,
                              hipStream_t stream) {
    const int*   idx = (const int*)d_in[0];
    const float* w1  = (const float*)d_in[1];
    const float* b1  = (const float*)d_in[2];
    const float* w2  = (const float*)d_in[3];
    const float* b2  = (const float*)d_in[4];
    float* out = (float*)d_out;
    const int ntok = in_sizes[0];   // 8*4096 = 32768

    const size_t table_bytes = (size_t)VOCAB * LABELS * sizeof(float);  // ~12.9 MB
    const int nblk2 = (ntok * 16 + 255) / 256;                          // 2048

    if (ws_size >= (size_t)KSPLIT * table_bytes + 1024) {
        // fast path: KSPLIT=2 MFMA build with merged bias block
        float* P = (float*)d_ws;
        float* C = (float*)((char*)d_ws + (size_t)KSPLIT * table_bytes);
        int ntiles = (VOCAB + TILEV - 1) / TILEV;          // 786
        dim3 grid1(ntiles + 1, KSPLIT);                    // 787 x 2 (last x = bias)
        build_mfma<<<grid1, 128, 0, stream>>>(w1, w2, b1, b2, P, C);
        gather_out<<<nblk2, 256, 0, stream>>>(idx, P, C, out, ntok, KSPLIT);
    } else {
        int ksplit = 0;
        if      (ws_size >= 4 * table_bytes) ksplit = 4;
        else if (ws_size >= 2 * table_bytes) ksplit = 2;
        else if (ws_size >= 1 * table_bytes) ksplit = 1;
        if (ksplit > 0) {
            float* P = (float*)d_ws;
            dim3 grid1((VOCAB + 63) / 64, ksplit);
            build_partial_folded<<<grid1, 256, 0, stream>>>(w1, b1, w2, P, HID / ksplit);
            gather_out<<<nblk2, 256, 0, stream>>>(idx, P, b2, out, ntok, ksplit);
        } else {
            int nblk = (ntok * 64 + 255) / 256;
            direct_kernel<<<nblk, 256, 0, stream>>>(idx, w1, b1, w2, b2, out, ntok);
        }
    }
}